// Round 1
// baseline (489.559 us; speedup 1.0000x reference)
//
#include <hip/hip_runtime.h>

// out[b, n] = sum_k x[b,k] * w[n,k]
// B=8, S=1, K=4096, N=11008, fp32.
// HBM-bound on the 180 MB weight stream (floor ~29 us at 6.3 TB/s).
// Restructure vs previous version: longer barrier-free streaming phases
// (KC 1024->2048, barriers 8->4 per block) and 4 independent weight-row
// streams per wave (rows/wave 2->4) so the HBM pipe stays full instead of
// draining at every __syncthreads.

#define BATCH 8
#define KDIM 4096
#define NDIM 11008
#define KC 2048               // K-chunk staged into LDS: 8*2048*4 B = 64 KB
#define KC4 (KC / 4)          // 512 float4 per batch per chunk
#define BLOCK 512             // 8 waves
#define ROWS_PER_WAVE 4
#define ROWS_PER_BLOCK 32     // 8 waves * 4 rows

__global__ __launch_bounds__(BLOCK, 4)   // 4 waves/SIMD -> VGPR <= 128, 2 blocks/CU (LDS-capped)
void ActivationSparseLinear_4982162063725_kernel(const float* __restrict__ x,
                                                 const float* __restrict__ w,
                                                 float* __restrict__ out) {
    __shared__ float4 xs[BATCH * KC4];   // 8 batches x 512 float4 = 64 KB

    const int tid  = threadIdx.x;
    const int lane = tid & 63;
    const int wave = tid >> 6;
    const int n0   = blockIdx.x * ROWS_PER_BLOCK + wave * ROWS_PER_WAVE;

    const float4* xg4 = (const float4*)x;     // [BATCH][KDIM/4]
    const float4* wg4 = (const float4*)w;     // [NDIM][KDIM/4]

    float acc[ROWS_PER_WAVE][BATCH];
#pragma unroll
    for (int r = 0; r < ROWS_PER_WAVE; ++r)
#pragma unroll
        for (int b = 0; b < BATCH; ++b) acc[r][b] = 0.0f;

    const float4* wrow[ROWS_PER_WAVE];
#pragma unroll
    for (int r = 0; r < ROWS_PER_WAVE; ++r)
        wrow[r] = wg4 + (size_t)(n0 + r) * (KDIM / 4);

    for (int c = 0; c < KDIM / KC; ++c) {     // 2 chunks
        // Stage x[:, c*KC .. c*KC+KC) into LDS: 8 fully-coalesced 512-lane
        // float4 loads (x is L2-resident after the first few blocks touch it).
#pragma unroll
        for (int b = 0; b < BATCH; ++b)
            xs[b * KC4 + tid] = xg4[b * (KDIM / 4) + c * KC4 + tid];
        __syncthreads();

        const int cbase = c * KC4;
        // Barrier-free streaming window: 32 independent weight float4 per
        // thread (4 row-streams x 8 iterations) for the compiler to pipeline.
#pragma unroll
        for (int i = 0; i < KC4 / 64; ++i) {  // 8 iterations
            const int kk = i * 64 + lane;

            float4 wv[ROWS_PER_WAVE];         // 4 independent 1 KB/wave streams
#pragma unroll
            for (int r = 0; r < ROWS_PER_WAVE; ++r)
                wv[r] = wrow[r][cbase + kk];

            float4 xv[BATCH];                 // conflict-free ds_read_b128
#pragma unroll
            for (int b = 0; b < BATCH; ++b)
                xv[b] = xs[b * KC4 + kk];

#pragma unroll
            for (int r = 0; r < ROWS_PER_WAVE; ++r)
#pragma unroll
                for (int b = 0; b < BATCH; ++b)
                    acc[r][b] += wv[r].x * xv[b].x + wv[r].y * xv[b].y
                               + wv[r].z * xv[b].z + wv[r].w * xv[b].w;
        }
        __syncthreads();
    }

    // Butterfly-reduce each accumulator across the 64-lane wave.
#pragma unroll
    for (int r = 0; r < ROWS_PER_WAVE; ++r)
#pragma unroll
        for (int b = 0; b < BATCH; ++b) {
            float v = acc[r][b];
#pragma unroll
            for (int off = 32; off > 0; off >>= 1)
                v += __shfl_xor(v, off, 64);
            acc[r][b] = v;
        }

    if (lane == 0) {
#pragma unroll
        for (int r = 0; r < ROWS_PER_WAVE; ++r)
#pragma unroll
            for (int b = 0; b < BATCH; ++b)
                out[(size_t)b * NDIM + n0 + r] = acc[r][b];
    }
}

extern "C" void kernel_launch(void* const* d_in, const int* in_sizes, int n_in,
                              void* d_out, int out_size, void* d_ws, size_t ws_size,
                              hipStream_t stream) {
    const float* x = (const float*)d_in[0];   // (8, 1, 4096) fp32
    const float* w = (const float*)d_in[1];   // (11008, 4096) fp32
    float* out = (float*)d_out;               // (8, 1, 11008) fp32

    dim3 grid(NDIM / ROWS_PER_BLOCK);         // 344 blocks, exact fit
    ActivationSparseLinear_4982162063725_kernel<<<grid, BLOCK, 0, stream>>>(x, w, out);
}

// Round 2
// 251.451 us; speedup vs baseline: 1.9469x; 1.9469x over previous
//
#include <hip/hip_runtime.h>

// out[b, n] = sum_k x[b,k] * w[n,k]
// B=8, S=1, K=4096, N=11008, fp32.
// HBM-bound on the 180 MB weight stream (floor ~29 us at 6.3 TB/s).
//
// Round-1 post-mortem: __launch_bounds__(512,4) capped VGPRs at 64 for a loop
// needing ~110 -> scratch spills (WRITE_SIZE 504 MB, VALUBusy 2.8%). Fix:
// 256-thread blocks with a 128-VGPR budget, and drop LDS/barriers entirely --
// x is 128 KB (L2-resident, L1-hot), so read it directly. Pure streaming loop:
// 4 independent weight-row streams per wave, 12 independent loads per
// iteration, zero __syncthreads, nothing to drain the HBM pipe.

#define BATCH 8
#define KDIM 4096
#define NDIM 11008
#define BLOCK 256             // 4 waves
#define ROWS_PER_WAVE 4
#define ROWS_PER_BLOCK 16     // 4 waves * 4 rows

__global__ __launch_bounds__(BLOCK, 4)   // 16 waves/CU target -> VGPR budget 128, no spill
void ActivationSparseLinear_4982162063725_kernel(const float* __restrict__ x,
                                                 const float* __restrict__ w,
                                                 float* __restrict__ out) {
    const int tid  = threadIdx.x;
    const int lane = tid & 63;
    const int wave = tid >> 6;
    const int n0   = blockIdx.x * ROWS_PER_BLOCK + wave * ROWS_PER_WAVE;

    const float4* xg4 = (const float4*)x;     // [BATCH][KDIM/4]
    const float4* wg4 = (const float4*)w;     // [NDIM][KDIM/4]

    float acc[ROWS_PER_WAVE][BATCH];
#pragma unroll
    for (int r = 0; r < ROWS_PER_WAVE; ++r)
#pragma unroll
        for (int b = 0; b < BATCH; ++b) acc[r][b] = 0.0f;

    const float4* wrow0 = wg4 + (size_t)(n0 + 0) * (KDIM / 4);
    const float4* wrow1 = wg4 + (size_t)(n0 + 1) * (KDIM / 4);
    const float4* wrow2 = wg4 + (size_t)(n0 + 2) * (KDIM / 4);
    const float4* wrow3 = wg4 + (size_t)(n0 + 3) * (KDIM / 4);

    // 16 iterations cover K=4096 (64 lanes x 4 floats x 16). Each iteration
    // issues 4 coalesced 1 KB/wave weight loads (HBM stream) + 8 x loads
    // (L1/L2-hit) -- 12 independent loads for the scheduler to pipeline.
#pragma unroll 2
    for (int i = 0; i < KDIM / 4 / 64; ++i) {
        const int kk = i * 64 + lane;

        float4 w0 = wrow0[kk];
        float4 w1 = wrow1[kk];
        float4 w2 = wrow2[kk];
        float4 w3 = wrow3[kk];

        float4 xv[BATCH];
#pragma unroll
        for (int b = 0; b < BATCH; ++b)
            xv[b] = xg4[b * (KDIM / 4) + kk];

#pragma unroll
        for (int b = 0; b < BATCH; ++b) {
            acc[0][b] += w0.x * xv[b].x + w0.y * xv[b].y + w0.z * xv[b].z + w0.w * xv[b].w;
            acc[1][b] += w1.x * xv[b].x + w1.y * xv[b].y + w1.z * xv[b].z + w1.w * xv[b].w;
            acc[2][b] += w2.x * xv[b].x + w2.y * xv[b].y + w2.z * xv[b].z + w2.w * xv[b].w;
            acc[3][b] += w3.x * xv[b].x + w3.y * xv[b].y + w3.z * xv[b].z + w3.w * xv[b].w;
        }
    }

    // Butterfly-reduce each accumulator across the 64-lane wave.
#pragma unroll
    for (int r = 0; r < ROWS_PER_WAVE; ++r)
#pragma unroll
        for (int b = 0; b < BATCH; ++b) {
            float v = acc[r][b];
#pragma unroll
            for (int off = 32; off > 0; off >>= 1)
                v += __shfl_xor(v, off, 64);
            acc[r][b] = v;
        }

    if (lane == 0) {
#pragma unroll
        for (int r = 0; r < ROWS_PER_WAVE; ++r)
#pragma unroll
            for (int b = 0; b < BATCH; ++b)
                out[(size_t)b * NDIM + n0 + r] = acc[r][b];
    }
}

extern "C" void kernel_launch(void* const* d_in, const int* in_sizes, int n_in,
                              void* d_out, int out_size, void* d_ws, size_t ws_size,
                              hipStream_t stream) {
    const float* x = (const float*)d_in[0];   // (8, 1, 4096) fp32
    const float* w = (const float*)d_in[1];   // (11008, 4096) fp32
    float* out = (float*)d_out;               // (8, 1, 11008) fp32

    dim3 grid(NDIM / ROWS_PER_BLOCK);         // 688 blocks, exact fit
    ActivationSparseLinear_4982162063725_kernel<<<grid, BLOCK, 0, stream>>>(x, w, out);
}